// Round 3
// baseline (8624.899 us; speedup 1.0000x reference)
//
#include <hip/hip_runtime.h>
#include <math.h>

#define Bsz 512
#define Nn  24
#define Tt  25
#define NG  8            // groups; group g = blocks with blockIdx.x % NG == g
// IN=8, L=64, H=256, OUT=128
// layer1: per-step K = 8(loc,locd) + 128(h1) -> padded 192; z-part hoisted to base1
// layer2: K=256; fc: K=128; init: K=256 from enc (fp32)

typedef _Float16 f16;
typedef _Float16 f16x8 __attribute__((ext_vector_type(8)));
typedef _Float16 f16x4 __attribute__((ext_vector_type(4)));
typedef float f32x4 __attribute__((ext_vector_type(4)));

// ---------------------------------------------------------------------------
// MFMA fp16 GEMM (standalone) — init path only (fp32 activations).
// ---------------------------------------------------------------------------
template <int FM, int FN>
__global__ __launch_bounds__(256) void gemm_mfma(
    const f16* __restrict__ Act, const float* __restrict__ Act32, int Ka,
    const f16* __restrict__ W, size_t wstride,
    const float* __restrict__ bias, int bstride,
    const f16* __restrict__ base16,
    f16* __restrict__ Y, int O)
{
    const int BM = FM * 32, BN = FN * 32;
    const int n  = blockIdx.z;
    const int o0 = blockIdx.x * BM;
    const int b0 = blockIdx.y * BN;
    const int tid  = threadIdx.x;
    const int wave = tid >> 6, lane = tid & 63;
    const int wm = (wave >> 1) * FM * 16;
    const int wn = (wave & 1) * FN * 16;
    const int m16 = lane & 15, quad = lane >> 4;

    __shared__ __attribute__((aligned(16))) f16 sW[BM][72];
    __shared__ __attribute__((aligned(16))) f16 sB[BN][72];

    const f16* Wn = W + (size_t)n * wstride;
    f32x4 acc[FM][FN] = {};

    const int r  = tid >> 3;
    const int cc = (tid & 7) * 8;

    for (int k0 = 0; k0 < Ka; k0 += 64) {
        for (int row = r; row < BM; row += 32)
            *(f16x8*)&sW[row][cc] = *(const f16x8*)&Wn[(size_t)(o0 + row) * Ka + k0 + cc];
        if (Act) {
            for (int row = r; row < BN; row += 32)
                *(f16x8*)&sB[row][cc] = *(const f16x8*)&Act[((size_t)(b0 + row) * Nn + n) * Ka + k0 + cc];
        } else {
            for (int row = r; row < BN; row += 32) {
                const float* src = &Act32[((size_t)(b0 + row) * Nn + n) * Ka + k0 + cc];
                f16x8 v;
#pragma unroll
                for (int u = 0; u < 8; u++) v[u] = (f16)src[u];
                *(f16x8*)&sB[row][cc] = v;
            }
        }
        __syncthreads();
#pragma unroll
        for (int kk = 0; kk < 64; kk += 32) {
            f16x8 af[FM], bf[FN];
#pragma unroll
            for (int i = 0; i < FM; i++)
                af[i] = *(const f16x8*)&sW[wm + i * 16 + m16][kk + quad * 8];
#pragma unroll
            for (int j = 0; j < FN; j++)
                bf[j] = *(const f16x8*)&sB[wn + j * 16 + m16][kk + quad * 8];
#pragma unroll
            for (int i = 0; i < FM; i++)
#pragma unroll
                for (int j = 0; j < FN; j++)
                    acc[i][j] = __builtin_amdgcn_mfma_f32_16x16x32_f16(af[i], bf[j], acc[i][j], 0, 0, 0);
        }
        __syncthreads();
    }
#pragma unroll
    for (int i = 0; i < FM; i++) {
        const int orow = o0 + wm + i * 16 + quad * 4;
        float4 bv = make_float4(0.f, 0.f, 0.f, 0.f);
        if (bias) bv = *(const float4*)&bias[(size_t)n * bstride + orow];
#pragma unroll
        for (int j = 0; j < FN; j++) {
            const int bcol = b0 + wn + j * 16 + m16;
            size_t yi = ((size_t)bcol * Nn + n) * (size_t)O + orow;
            float v0 = acc[i][j][0] + bv.x;
            float v1 = acc[i][j][1] + bv.y;
            float v2 = acc[i][j][2] + bv.z;
            float v3 = acc[i][j][3] + bv.w;
            if (base16) {
                f16x4 bb = *(const f16x4*)&base16[yi];
                v0 += (float)bb[0]; v1 += (float)bb[1];
                v2 += (float)bb[2]; v3 += (float)bb[3];
            }
            f16x4 o4; o4[0] = (f16)v0; o4[1] = (f16)v1; o4[2] = (f16)v2; o4[3] = (f16)v3;
            *(f16x4*)&Y[yi] = o4;
        }
    }
}

// ---------------------------------------------------------------------------
// Weight prep kernels
// ---------------------------------------------------------------------------
__global__ __launch_bounds__(256) void prep_w01(
    const float* __restrict__ Wx0, const float* __restrict__ Wh0,
    const float* __restrict__ Wx1, const float* __restrict__ Wh1,
    f16* __restrict__ Wz, f16* __restrict__ Wt0, f16* __restrict__ Wt1)
{
    size_t idx = (size_t)blockIdx.x * 256 + threadIdx.x;
    const size_t nz = (size_t)Nn * 512 * 64;
    const size_t n0 = (size_t)Nn * 512 * 192;
    const size_t n1 = (size_t)Nn * 512 * 256;
    if (idx < nz) {
        int k = idx & 63; int o = (idx >> 6) & 511; int n = (int)(idx >> 15);
        Wz[idx] = (f16)Wx0[((size_t)n * 72 + k) * 512 + o];
    } else if (idx < nz + n0) {
        size_t i2 = idx - nz;
        int k = (int)(i2 % 192);
        size_t no = i2 / 192;
        int o = (int)(no & 511); int n = (int)(no >> 9);
        float v = 0.f;
        if (k < 8) v = Wx0[((size_t)n * 72 + 64 + k) * 512 + o];
        else if (k < 136) v = Wh0[((size_t)n * 128 + (k - 8)) * 512 + o];
        Wt0[i2] = (f16)v;
    } else if (idx < nz + n0 + n1) {
        size_t i3 = idx - nz - n0;
        int k = (int)(i3 & 255);
        size_t no = i3 >> 8;
        int o = (int)(no & 511); int n = (int)(no >> 9);
        float v = (k < 128) ? Wx1[((size_t)n * 128 + k) * 512 + o]
                            : Wh1[((size_t)n * 128 + (k - 128)) * 512 + o];
        Wt1[i3] = (f16)v;
    }
}

__global__ __launch_bounds__(256) void prep_wf(
    const float* __restrict__ fcW, const float* __restrict__ fc2W,
    f16* __restrict__ Wtf)
{
    size_t idx = (size_t)blockIdx.x * 256 + threadIdx.x;
    if (idx >= (size_t)Nn * 256 * 128) return;
    int k = (int)(idx & 127);
    size_t no = idx >> 7;
    int o = (int)(no & 255); int n = (int)(no >> 8);
    float v = (o < 128) ? fcW[((size_t)n * 128 + k) * 128 + o]
                        : fc2W[((size_t)n * 128 + k) * 128 + (o - 128)];
    Wtf[idx] = (f16)v;
}

__global__ __launch_bounds__(256) void prep_wi(
    const float* __restrict__ ih1W, const float* __restrict__ ih2W,
    const float* __restrict__ ih1b, const float* __restrict__ ih2b,
    const float* __restrict__ fcb, const float* __restrict__ fc2b,
    f16* __restrict__ Wti, float* __restrict__ bi, float* __restrict__ bcat,
    unsigned* __restrict__ bar)
{
    int idx = blockIdx.x * 256 + threadIdx.x;
    int k = idx & 255, o = idx >> 8;
    Wti[idx] = (f16)((o < 128) ? ih1W[(size_t)k * 128 + o] : ih2W[(size_t)k * 128 + (o - 128)]);
    if (idx < 256) bi[idx] = (idx < 128) ? ih1b[idx] : ih2b[idx - 128];
    if (idx < Nn * 256) {
        int n = idx >> 8, oo = idx & 255;
        bcat[idx] = (oo < 128) ? fcb[n * 128 + oo] : fc2b[n * 128 + (oo - 128)];
    }
    if (idx < NG * 2 * 64) bar[idx] = 0u;   // zero the barrier lines (2 chains/group)
}

__global__ __launch_bounds__(256) void init_xi(
    const float* __restrict__ x, f16* __restrict__ xi2, float* __restrict__ ls)
{
    size_t idx = (size_t)blockIdx.x * 256 + threadIdx.x;
    const size_t total = (size_t)Bsz * Nn * 192;
    if (idx < total) {
        size_t bn = idx / 192;
        int k = (int)(idx - bn * 192);
        if (k < 8) xi2[idx] = (f16)x[bn * 8 + k];
        else if (k >= 136) xi2[idx] = (f16)0.f;
    }
    if (idx < (size_t)Bsz * Nn * 4) {
        size_t bn = idx >> 2;
        ls[idx] = x[bn * 8 + (idx & 3)];
    }
}

__global__ __launch_bounds__(256) void mix_init(
    const f16* __restrict__ Yhc, const float* __restrict__ G,
    f16* __restrict__ xi2, f16* __restrict__ l2cat,
    float* __restrict__ c1, float* __restrict__ c2)
{
    const int b = blockIdx.x;
    const int tid = threadIdx.x;
    __shared__ float sY[6144], sG[576];
    for (int i = tid; i < 576; i += 256) sG[i] = G[i];
    for (int v = tid; v < 768; v += 256) {
        int c8 = (v & 31) * 8, n = v >> 5;
        f16x8 t = *(const f16x8*)&Yhc[((size_t)b * Nn + n) * 256 + c8];
        float* d = &sY[n * 256 + c8];
#pragma unroll
        for (int u = 0; u < 8; u++) d[u] = (float)t[u];
    }
    __syncthreads();
    for (int w = tid; w < 3072; w += 256) {
        int o = w & 127, m = w >> 7;
        float ah = 0.f, ac = 0.f;
#pragma unroll
        for (int n = 0; n < 24; n++) {
            float g = sG[m * 24 + n];
            ah += g * sY[n * 256 + o];
            ac += g * sY[n * 256 + 128 + o];
        }
        size_t row = (size_t)b * Nn + m;
        f16 hf = (f16)ah;
        xi2[row * 192 + 8 + o] = hf;
        l2cat[row * 256 + o] = hf;
        l2cat[row * 256 + 128 + o] = hf;
        c1[row * 128 + o] = ac;
        c2[row * 128 + o] = ac;
    }
}

// ===========================================================================
// Persistent step-loop with split-phase group barriers + 2-chain pipelining.
// Group g (blockIdx.x % NG) owns batch rows [g*64, g*64+64), split into
// chain A = rows [b0,b0+32), chain B = rows [b0+32,b0+64). Chains are fully
// independent (only nodes couple, via G — never batch rows), so each chain
// has its own barrier and the interleave hides barrier latency.
// ===========================================================================
struct StepArgs {
    const float* G;
    const f16* Wt0; const f16* Wt1; const f16* Wtf;
    const float* b1i; const float* bcat;
    const f16* base1;
    f16* xi2; f16* l2cat; f16* yib; f16* yp; f16* pbuf;
    float* c1; float* c2; float* ls;
    const float* locW; const float* locb; const float* lzW; const float* lzb;
    float* out;
    unsigned* bar;
    int KB;          // blocks per group
};

#define SMEM_BYTES 50688

// Barrier: cnt at gb[0], epoch at gb[32] (same 256B line).
// arrive: release fetch_add (1 wb per block); last arriver resets cnt and
// release-publishes epoch. wait: RELAXED spin (no cache maintenance!) +
// one acquire fence after exit.
__device__ __forceinline__ void bar_arrive(unsigned* gb, unsigned members, int tid)
{
    __syncthreads();
    if (tid == 0) {
        unsigned old = __hip_atomic_fetch_add(&gb[0], 1u, __ATOMIC_RELEASE,
                                              __HIP_MEMORY_SCOPE_AGENT);
        if (old == members - 1u) {
            __hip_atomic_store(&gb[0], 0u, __ATOMIC_RELAXED, __HIP_MEMORY_SCOPE_AGENT);
            __hip_atomic_fetch_add(&gb[32], 1u, __ATOMIC_RELEASE,
                                   __HIP_MEMORY_SCOPE_AGENT);
        }
    }
}

__device__ __forceinline__ void bar_wait(unsigned* gb, unsigned target, int tid)
{
    if (tid == 0) {
        while (__hip_atomic_load(&gb[32], __ATOMIC_RELAXED,
                                 __HIP_MEMORY_SCOPE_AGENT) < target)
            __builtin_amdgcn_s_sleep(2);
    }
    __syncthreads();
    __builtin_amdgcn_fence(__ATOMIC_ACQUIRE, "agent");
}

// ---- GEMM jobs: (ntx o-tiles) x 24 n over a 32-row b-slice (BN=32) ----
template <int FM, int FN>
__device__ __forceinline__ void gemm_jobs(
    char* smraw,
    const f16* __restrict__ Act, int Ka,
    const f16* __restrict__ W, size_t wstride,
    const float* __restrict__ bias, int bstride,
    const f16* __restrict__ base16,
    f16* __restrict__ Y, int O,
    int b0c, int ntx, int njobs,
    int rank, int KB, int tid)
{
    const int BM = FM * 32, BN = FN * 32;
    f16 (*sW)[72] = (f16 (*)[72])smraw;
    f16 (*sB)[72] = (f16 (*)[72])(smraw + (size_t)BM * 72 * 2);
    const int wave = tid >> 6, lane = tid & 63;
    const int wm = (wave >> 1) * FM * 16;
    const int wn = (wave & 1) * FN * 16;
    const int m16 = lane & 15, quad = lane >> 4;
    const int r  = tid >> 3;
    const int cc = (tid & 7) * 8;

    for (int j = rank; j < njobs; j += KB) {
        const int n  = j / ntx;
        const int o0 = (j - n * ntx) * BM;
        const f16* Wn = W + (size_t)n * wstride;
        f32x4 acc[FM][FN] = {};

        for (int k0 = 0; k0 < Ka; k0 += 64) {
            for (int row = r; row < BM; row += 32)
                *(f16x8*)&sW[row][cc] = *(const f16x8*)&Wn[(size_t)(o0 + row) * Ka + k0 + cc];
            for (int row = r; row < BN; row += 32)
                *(f16x8*)&sB[row][cc] = *(const f16x8*)&Act[((size_t)(b0c + row) * Nn + n) * Ka + k0 + cc];
            __syncthreads();
#pragma unroll
            for (int kk = 0; kk < 64; kk += 32) {
                f16x8 af[FM], bf[FN];
#pragma unroll
                for (int i = 0; i < FM; i++)
                    af[i] = *(const f16x8*)&sW[wm + i * 16 + m16][kk + quad * 8];
#pragma unroll
                for (int jj = 0; jj < FN; jj++)
                    bf[jj] = *(const f16x8*)&sB[wn + jj * 16 + m16][kk + quad * 8];
#pragma unroll
                for (int i = 0; i < FM; i++)
#pragma unroll
                    for (int jj = 0; jj < FN; jj++)
                        acc[i][jj] = __builtin_amdgcn_mfma_f32_16x16x32_f16(af[i], bf[jj], acc[i][jj], 0, 0, 0);
            }
            __syncthreads();
        }
#pragma unroll
        for (int i = 0; i < FM; i++) {
            const int orow = o0 + wm + i * 16 + quad * 4;
            float4 bv = make_float4(0.f, 0.f, 0.f, 0.f);
            if (bias) bv = *(const float4*)&bias[(size_t)n * bstride + orow];
#pragma unroll
            for (int jj = 0; jj < FN; jj++) {
                const int bcol = b0c + wn + jj * 16 + m16;
                size_t yi = ((size_t)bcol * Nn + n) * (size_t)O + orow;
                float v0 = acc[i][jj][0] + bv.x;
                float v1 = acc[i][jj][1] + bv.y;
                float v2 = acc[i][jj][2] + bv.z;
                float v3 = acc[i][jj][3] + bv.w;
                if (base16) {
                    f16x4 bb = *(const f16x4*)&base16[yi];
                    v0 += (float)bb[0]; v1 += (float)bb[1];
                    v2 += (float)bb[2]; v3 += (float)bb[3];
                }
                f16x4 o4; o4[0] = (f16)v0; o4[1] = (f16)v1; o4[2] = (f16)v2; o4[3] = (f16)v3;
                *(f16x4*)&Y[yi] = o4;
            }
        }
    }
}

// ---- mixlstm jobs: nb b-rows x 2 jt ----
__device__ __forceinline__ void mixlstm_jobs(
    char* smraw, const float* sG,
    const f16* __restrict__ Ypre, float* __restrict__ c,
    f16* __restrict__ dstA, int strideA,
    f16* __restrict__ dstB, int strideB, int tanhB,
    int b0c, int nb, int rank, int KB, int tid)
{
    float* sY = (float*)smraw;
    for (int vt = rank; vt < 2 * nb; vt += KB) {
        const int b  = b0c + (vt % nb);
        const int jt = (vt / nb) * 64;
        for (int v = tid; v < 768; v += 256) {
            int j8 = (v & 7) * 8, g = (v >> 3) & 3, n = v >> 5;
            f16x8 t = *(const f16x8*)&Ypre[((size_t)b * Nn + n) * 512 + g * 128 + jt + j8];
            float* d = &sY[n * 256 + g * 64 + j8];
#pragma unroll
            for (int u = 0; u < 8; u++) d[u] = (float)t[u];
        }
        __syncthreads();
        for (int w = tid; w < 1536; w += 256) {
            int j = w & 63, m = w >> 6;
            float gi = 0.f, gf = 0.f, gg = 0.f, go = 0.f;
            const float* gr = &sG[m * 24];
#pragma unroll
            for (int n = 0; n < 24; n++) {
                float g = gr[n];
                gi += g * sY[n * 256 + j];
                gf += g * sY[n * 256 + 64 + j];
                gg += g * sY[n * 256 + 128 + j];
                go += g * sY[n * 256 + 192 + j];
            }
            int col = jt + j;
            size_t row = (size_t)b * Nn + m;
            float cv = c[row * 128 + col];
            float si = 1.f / (1.f + expf(-gi));
            float sf = 1.f / (1.f + expf(-gf));
            float so = 1.f / (1.f + expf(-go));
            float tg = tanhf(gg);
            cv = sf * cv + si * tg;
            c[row * 128 + col] = cv;
            float h = so * tanhf(cv);
            dstA[row * strideA + col] = (f16)h;
            dstB[row * strideB + col] = (f16)(tanhB ? tanhf(h) : h);
        }
        __syncthreads();
    }
}

// ---- finstep jobs: 64 b (whole group) ----
__device__ __forceinline__ void finstep_jobs(
    char* smraw, const float* sG,
    const f16* __restrict__ p,
    const float* __restrict__ locW, const float* __restrict__ locb,
    const float* __restrict__ lzW, const float* __restrict__ lzb,
    float* __restrict__ ls, f16* __restrict__ xi2,
    float* __restrict__ out, int t,
    int b0, int rank, int KB, int tid)
{
    float* sP  = (float*)smraw;
    float* sY1 = (float*)(smraw + 24576);
    float* sY2 = (float*)(smraw + 36864);
    float (*sLp)[3] = (float (*)[3])(smraw + 49152);
    float (*sZp)[4] = (float (*)[4])(smraw + 49440);
    float (*sL3)[3] = (float (*)[3])(smraw + 49824);
    float (*sZ3)[4] = (float (*)[4])(smraw + 50112);

    for (int vb = rank; vb < 64; vb += KB) {
        const int b = b0 + vb;
        for (int v = tid; v < 768; v += 256) {
            int c8 = (v & 31) * 8, n = v >> 5;
            f16x8 tv = *(const f16x8*)&p[((size_t)b * Nn + n) * 256 + c8];
            float* d = &sP[n * 256 + c8];
#pragma unroll
            for (int u = 0; u < 8; u++) d[u] = (float)tv[u];
        }
        __syncthreads();
        for (int w = tid; w < 3072; w += 256) {
            int o = w & 127, m = w >> 7;
            float a1 = 0.f, a2 = 0.f;
#pragma unroll
            for (int n = 0; n < 24; n++) {
                float g = sG[m * 24 + n];
                a1 += g * sP[n * 256 + o];
                a2 += g * sP[n * 256 + 128 + o];
            }
            sY1[w] = tanhf(a1);
            sY2[w] = tanhf(a2);
        }
        __syncthreads();
        if (tid < 72) {
            int m = tid / 3, j = tid - m * 3;
            float s = locb[j];
            for (int o = 0; o < 128; o++) s += sY1[m * 128 + o] * locW[o * 3 + j];
            sLp[m][j] = s;
        } else if (tid < 168) {
            int w2 = tid - 72; int m = w2 >> 2, j = w2 & 3;
            float s = lzb[j];
            for (int o = 0; o < 128; o++) s += sY2[m * 128 + o] * lzW[o * 4 + j];
            sZp[m][j] = s;
        }
        __syncthreads();
        if (tid < 72) {
            int m = tid / 3, j = tid - m * 3;
            float s = 0.f;
#pragma unroll
            for (int n = 0; n < 24; n++) s += sG[m * 24 + n] * sLp[n][j];
            sL3[m][j] = s;
        } else if (tid < 168) {
            int w2 = tid - 72; int m = w2 >> 2, j = w2 & 3;
            float s = 0.f;
#pragma unroll
            for (int n = 0; n < 24; n++) s += sG[m * 24 + n] * sZp[n][j];
            sZ3[m][j] = s;
        }
        __syncthreads();
        if (tid < 24) {
            int m = tid;
            float xx = sL3[m][0], xy = sL3[m][1], xz = sL3[m][2];
            float r = rsqrtf(1.f + xx * xx + xy * xy + xz * xz);
            float dw = r, dx = xx * r, dy = xy * r, dz = xz * r;
            size_t li = ((size_t)b * Nn + m) * 4;
            float qw = ls[li], qx = ls[li + 1], qy = ls[li + 2], qz = ls[li + 3];
            float lw = qw * dw - qx * dx - qy * dy - qz * dz;
            float lx = qw * dx + qx * dw + qy * dz - qz * dy;
            float ly = qw * dy - qx * dz + qy * dw + qz * dx;
            float lz = qw * dz + qx * dy - qy * dx + qz * dw;
            size_t oi = (((size_t)b * Tt + t) * Nn + m) * 4;
            out[oi + 0] = lw; out[oi + 1] = lx; out[oi + 2] = ly; out[oi + 3] = lz;
            size_t zi = (size_t)Bsz * Tt * Nn * 4 + oi;
            out[zi + 0] = sZ3[m][0]; out[zi + 1] = sZ3[m][1];
            out[zi + 2] = sZ3[m][2]; out[zi + 3] = sZ3[m][3];
            ls[li] = lw; ls[li + 1] = lx; ls[li + 2] = ly; ls[li + 3] = lz;
            size_t xb = ((size_t)b * Nn + m) * 192;
            xi2[xb + 0] = (f16)lw; xi2[xb + 1] = (f16)lx; xi2[xb + 2] = (f16)ly; xi2[xb + 3] = (f16)lz;
            xi2[xb + 4] = (f16)dw; xi2[xb + 5] = (f16)dx; xi2[xb + 6] = (f16)dy; xi2[xb + 7] = (f16)dz;
        }
        __syncthreads();
    }
}

__global__ __launch_bounds__(256, 2) void step_loop_p(StepArgs a)
{
    __shared__ float sG[576];
    __shared__ __attribute__((aligned(16))) char smem[SMEM_BYTES];

    const int tid  = threadIdx.x;
    const int KB   = a.KB;
    const int g    = blockIdx.x % NG;       // round-robin dispatch -> same-XCD group
    const int rank = blockIdx.x / NG;
    const int b0   = g * (Bsz / NG);        // 64 rows per group
    const int bA   = b0, bB = b0 + 32;      // two 32-row chains
    unsigned* barA = a.bar + (size_t)(g * 2 + 0) * 64;
    unsigned* barB = a.bar + (size_t)(g * 2 + 1) * 64;
    const unsigned members = (unsigned)KB;

    for (int i = tid; i < 576; i += 256) sG[i] = a.G[i];
    __syncthreads();

    unsigned tA = 0, tB = 0;
    for (int t = 0; t < Tt; t++) {
        // ---- layer-1 gates: yp = xi2 . Wt0 + base1  (O=512, K=192) ----
        bar_wait(barA, tA, tid);
        gemm_jobs<2, 1>(smem, a.xi2, 192, a.Wt0, (size_t)512 * 192,
                        nullptr, 0, a.base1, a.yp, 512, bA, 8, 192, rank, KB, tid);
        bar_arrive(barA, members, tid); tA++;

        bar_wait(barB, tB, tid);
        gemm_jobs<2, 1>(smem, a.xi2, 192, a.Wt0, (size_t)512 * 192,
                        nullptr, 0, a.base1, a.yp, 512, bB, 8, 192, rank, KB, tid);
        bar_arrive(barB, members, tid); tB++;

        // ---- LSTM-1 mix ----
        bar_wait(barA, tA, tid);
        mixlstm_jobs(smem, sG, a.yp, a.c1, a.xi2 + 8, 192, a.l2cat, 256, 0,
                     bA, 32, rank, KB, tid);
        bar_arrive(barA, members, tid); tA++;

        bar_wait(barB, tB, tid);
        mixlstm_jobs(smem, sG, a.yp, a.c1, a.xi2 + 8, 192, a.l2cat, 256, 0,
                     bB, 32, rank, KB, tid);
        bar_arrive(barB, members, tid); tB++;

        // ---- layer-2 gates: yp = l2cat . Wt1 + b1  (O=512, K=256) ----
        bar_wait(barA, tA, tid);
        gemm_jobs<2, 1>(smem, a.l2cat, 256, a.Wt1, (size_t)512 * 256,
                        a.b1i, 512, nullptr, a.yp, 512, bA, 8, 192, rank, KB, tid);
        bar_arrive(barA, members, tid); tA++;

        bar_wait(barB, tB, tid);
        gemm_jobs<2, 1>(smem, a.l2cat, 256, a.Wt1, (size_t)512 * 256,
                        a.b1i, 512, nullptr, a.yp, 512, bB, 8, 192, rank, KB, tid);
        bar_arrive(barB, members, tid); tB++;

        // ---- LSTM-2 mix ----
        bar_wait(barA, tA, tid);
        mixlstm_jobs(smem, sG, a.yp, a.c2, a.l2cat + 128, 256, a.yib, 128, 1,
                     bA, 32, rank, KB, tid);
        bar_arrive(barA, members, tid); tA++;

        bar_wait(barB, tB, tid);
        mixlstm_jobs(smem, sG, a.yp, a.c2, a.l2cat + 128, 256, a.yib, 128, 1,
                     bB, 32, rank, KB, tid);
        bar_arrive(barB, members, tid); tB++;

        // ---- fc heads: pbuf = yib . Wtf + bcat  (O=256, K=128) ----
        bar_wait(barA, tA, tid);
        gemm_jobs<1, 1>(smem, a.yib, 128, a.Wtf, (size_t)256 * 128,
                        a.bcat, 256, nullptr, a.pbuf, 256, bA, 8, 192, rank, KB, tid);
        bar_arrive(barA, members, tid); tA++;

        bar_wait(barB, tB, tid);
        gemm_jobs<1, 1>(smem, a.yib, 128, a.Wtf, (size_t)256 * 128,
                        a.bcat, 256, nullptr, a.pbuf, 256, bB, 8, 192, rank, KB, tid);
        bar_arrive(barB, members, tid); tB++;

        // ---- finstep over all 64 rows (64 jobs = balanced) ----
        bar_wait(barA, tA, tid);
        bar_wait(barB, tB, tid);
        finstep_jobs(smem, sG, a.pbuf, a.locW, a.locb, a.lzW, a.lzb,
                     a.ls, a.xi2, a.out, t, b0, rank, KB, tid);
        bar_arrive(barA, members, tid); tA++;
        bar_arrive(barB, members, tid); tB++;
    }
}

extern "C" void kernel_launch(void* const* d_in, const int* in_sizes, int n_in,
                              void* d_out, int out_size, void* d_ws, size_t ws_size,
                              hipStream_t stream)
{
    const float* x    = (const float*)d_in[0];
    const float* enc  = (const float*)d_in[1];
    const float* z    = (const float*)d_in[2];
    const float* G    = (const float*)d_in[4];
    const float* Wx0  = (const float*)d_in[5];
    const float* Wh0  = (const float*)d_in[6];
    const float* b0i  = (const float*)d_in[7];
    const float* Wx1  = (const float*)d_in[8];
    const float* Wh1  = (const float*)d_in[9];
    const float* b1i  = (const float*)d_in[10];
    const float* fcW  = (const float*)d_in[11];
    const float* fcb  = (const float*)d_in[12];
    const float* fc2W = (const float*)d_in[13];
    const float* fc2b = (const float*)d_in[14];
    const float* ih1W = (const float*)d_in[15];
    const float* ih1b = (const float*)d_in[16];
    const float* ih2W = (const float*)d_in[17];
    const float* ih2b = (const float*)d_in[18];
    const float* locW = (const float*)d_in[19];
    const float* locb = (const float*)d_in[20];
    const float* lzW  = (const float*)d_in[21];
    const float* lzb  = (const float*)d_in[22];
    float* out = (float*)d_out;

    const size_t BN = (size_t)Bsz * Nn;
    char* wp = (char*)d_ws;
    size_t off = 0;
    auto carve = [&](size_t bytes) -> char* {
        char* pc = wp + off;
        off += (bytes + 255) & ~(size_t)255;
        return pc;
    };
    f16*   Wz     = (f16*)carve((size_t)Nn * 512 * 64 * 2);
    f16*   Wt0    = (f16*)carve((size_t)Nn * 512 * 192 * 2);
    f16*   Wt1    = (f16*)carve((size_t)Nn * 512 * 256 * 2);
    f16*   Wtf    = (f16*)carve((size_t)Nn * 256 * 128 * 2);
    f16*   Wti    = (f16*)carve((size_t)256 * 256 * 2);
    float* bcat   = (float*)carve((size_t)Nn * 256 * 4);
    float* bi     = (float*)carve(256 * 4);
    f16*   base1  = (f16*)carve(BN * 512 * 2);
    f16*   xi2    = (f16*)carve(BN * 192 * 2);
    f16*   l2cat  = (f16*)carve(BN * 256 * 2);
    f16*   yib    = (f16*)carve(BN * 128 * 2);
    float* c1     = (float*)carve(BN * 128 * 4);
    float* c2     = (float*)carve(BN * 128 * 4);
    float* ls     = (float*)carve(BN * 4 * 4);
    f16*   yp     = (f16*)carve(BN * 512 * 2);
    f16*   pbuf   = (f16*)carve(BN * 256 * 2);
    unsigned* bar = (unsigned*)carve((size_t)NG * 2 * 64 * 4);

    // ---- one-time prep ----
    prep_w01<<<24576, 256, 0, stream>>>(Wx0, Wh0, Wx1, Wh1, Wz, Wt0, Wt1);
    prep_wf<<<3072, 256, 0, stream>>>(fcW, fc2W, Wtf);
    prep_wi<<<256, 256, 0, stream>>>(ih1W, ih2W, ih1b, ih2b, fcb, fc2b, Wti, bi, bcat, bar);
    init_xi<<<9216, 256, 0, stream>>>(x, xi2, ls);

    // base1 = z . Wx0[:,:64,:] + b0    (constant over all T steps)
    gemm_mfma<2, 4><<<dim3(8, 4, 24), 256, 0, stream>>>(
        nullptr, z, 64, Wz, (size_t)512 * 64, b0i, 512, nullptr, base1, 512);
    // init states: [h0|c0] from enc
    gemm_mfma<2, 4><<<dim3(4, 4, 24), 256, 0, stream>>>(
        nullptr, enc, 256, Wti, 0, bi, 0, nullptr, yp, 256);
    mix_init<<<512, 256, 0, stream>>>(yp, G, xi2, l2cat, c1, c2);

    // ---- persistent kernel ----
    StepArgs sa;
    sa.G = G; sa.Wt0 = Wt0; sa.Wt1 = Wt1; sa.Wtf = Wtf;
    sa.b1i = b1i; sa.bcat = bcat; sa.base1 = base1;
    sa.xi2 = xi2; sa.l2cat = l2cat; sa.yib = yib; sa.yp = yp; sa.pbuf = pbuf;
    sa.c1 = c1; sa.c2 = c2; sa.ls = ls;
    sa.locW = locW; sa.locb = locb; sa.lzW = lzW; sa.lzb = lzb;
    sa.out = out;
    sa.bar = bar;

    int maxb = 0;
    if (hipOccupancyMaxActiveBlocksPerMultiprocessor(&maxb, step_loop_p, 256, 0) != hipSuccess || maxb < 1)
        maxb = 1;
    int nblk = (maxb >= 2) ? 512 : 256;   // multiple of NG
    sa.KB = nblk / NG;

    void* kargs[] = { (void*)&sa };
    hipLaunchCooperativeKernel((const void*)step_loop_p, dim3(nblk), dim3(256),
                               kargs, 0, stream);
}

// Round 4
// 2348.722 us; speedup vs baseline: 3.6722x; 3.6722x over previous
//
#include <hip/hip_runtime.h>
#include <math.h>

#define Bsz 512
#define Nn  24
#define Tt  25
// IN=8, L=64, H=256, OUT=128
// layer1: per-step K = 8(loc,locd) + 128(h1) -> padded 192; z-part hoisted to base1
// layer2: K=256; fc: K=128; init: K=256 from enc (fp32)

typedef _Float16 f16;
typedef _Float16 f16x8 __attribute__((ext_vector_type(8)));
typedef _Float16 f16x4 __attribute__((ext_vector_type(4)));
typedef float f32x4 __attribute__((ext_vector_type(4)));

// ---------------------------------------------------------------------------
// MFMA fp16 GEMM, per-node block-diagonal, W-as-A orientation:
//   Y[b,n,o] = sum_k Act[b,n,k] * W[n,o,k] + bias[n,o] (+ base16[b,n,o])
// Register-prefetch pipelined K-loop: global loads for tile k+1 issue before
// the MFMA block of tile k, hiding L2/HBM latency under compute + barrier.
// Same arithmetic/LDS layout/MFMA order as the verified baseline.
// ---------------------------------------------------------------------------
template <int FM, int FN>
__global__ __launch_bounds__(256) void gemm_mfma(
    const f16* __restrict__ Act, const float* __restrict__ Act32, int Ka,
    const f16* __restrict__ W, size_t wstride,
    const float* __restrict__ bias, int bstride,
    const f16* __restrict__ base16,
    f16* __restrict__ Y, int O)
{
    const int BM = FM * 32, BN = FN * 32;
    const int n  = blockIdx.z;
    const int o0 = blockIdx.x * BM;
    const int b0 = blockIdx.y * BN;
    const int tid  = threadIdx.x;
    const int wave = tid >> 6, lane = tid & 63;
    const int wm = (wave >> 1) * FM * 16;   // o offset of wave
    const int wn = (wave & 1) * FN * 16;    // b offset of wave
    const int m16 = lane & 15, quad = lane >> 4;

    __shared__ __attribute__((aligned(16))) f16 sW[BM][72];  // o-rows, k-cols (+pad)
    __shared__ __attribute__((aligned(16))) f16 sB[BN][72];  // b-rows, k-cols

    const f16* Wn = W + (size_t)n * wstride;
    f32x4 acc[FM][FN] = {};

    const int r  = tid >> 3;        // staging row 0..31
    const int cc = (tid & 7) * 8;   // staging col (halfs)
    const int nk = Ka >> 6;         // 64-wide k tiles

    f16x8 rW[FM], rB[FN];
    float rBf[FN][8];

    // ---- prefetch k-tile 0 into registers ----
#pragma unroll
    for (int i = 0; i < FM; i++)
        rW[i] = *(const f16x8*)&Wn[(size_t)(o0 + r + 32 * i) * Ka + cc];
    if (Act) {
#pragma unroll
        for (int j = 0; j < FN; j++)
            rB[j] = *(const f16x8*)&Act[((size_t)(b0 + r + 32 * j) * Nn + n) * Ka + cc];
    } else {
#pragma unroll
        for (int j = 0; j < FN; j++) {
            const float* src = &Act32[((size_t)(b0 + r + 32 * j) * Nn + n) * Ka + cc];
#pragma unroll
            for (int u = 0; u < 8; u++) rBf[j][u] = src[u];
        }
    }

    for (int it = 0; it < nk; it++) {
        // ---- commit prefetched tile to LDS ----
#pragma unroll
        for (int i = 0; i < FM; i++)
            *(f16x8*)&sW[r + 32 * i][cc] = rW[i];
        if (Act) {
#pragma unroll
            for (int j = 0; j < FN; j++)
                *(f16x8*)&sB[r + 32 * j][cc] = rB[j];
        } else {
#pragma unroll
            for (int j = 0; j < FN; j++) {
                f16x8 v;
#pragma unroll
                for (int u = 0; u < 8; u++) v[u] = (f16)rBf[j][u];
                *(f16x8*)&sB[r + 32 * j][cc] = v;
            }
        }
        __syncthreads();

        // ---- issue next tile's global loads (latency hides under MFMA) ----
        if (it + 1 < nk) {
            const int k0n = (it + 1) << 6;
#pragma unroll
            for (int i = 0; i < FM; i++)
                rW[i] = *(const f16x8*)&Wn[(size_t)(o0 + r + 32 * i) * Ka + k0n + cc];
            if (Act) {
#pragma unroll
                for (int j = 0; j < FN; j++)
                    rB[j] = *(const f16x8*)&Act[((size_t)(b0 + r + 32 * j) * Nn + n) * Ka + k0n + cc];
            } else {
#pragma unroll
                for (int j = 0; j < FN; j++) {
                    const float* src = &Act32[((size_t)(b0 + r + 32 * j) * Nn + n) * Ka + k0n + cc];
#pragma unroll
                    for (int u = 0; u < 8; u++) rBf[j][u] = src[u];
                }
            }
        }

        // ---- MFMA on the committed LDS tile ----
#pragma unroll
        for (int kk = 0; kk < 64; kk += 32) {
            f16x8 af[FM], bf[FN];
#pragma unroll
            for (int i = 0; i < FM; i++)
                af[i] = *(const f16x8*)&sW[wm + i * 16 + m16][kk + quad * 8];
#pragma unroll
            for (int j = 0; j < FN; j++)
                bf[j] = *(const f16x8*)&sB[wn + j * 16 + m16][kk + quad * 8];
#pragma unroll
            for (int i = 0; i < FM; i++)
#pragma unroll
                for (int j = 0; j < FN; j++)
                    acc[i][j] = __builtin_amdgcn_mfma_f32_16x16x32_f16(af[i], bf[j], acc[i][j], 0, 0, 0);
        }
        __syncthreads();
    }
    // epilogue: D[row=o][col=b]; per lane, regs = 4 consecutive o at quad*4
#pragma unroll
    for (int i = 0; i < FM; i++) {
        const int orow = o0 + wm + i * 16 + quad * 4;
        float4 bv = make_float4(0.f, 0.f, 0.f, 0.f);
        if (bias) bv = *(const float4*)&bias[(size_t)n * bstride + orow];
#pragma unroll
        for (int j = 0; j < FN; j++) {
            const int bcol = b0 + wn + j * 16 + m16;
            size_t yi = ((size_t)bcol * Nn + n) * (size_t)O + orow;
            float v0 = acc[i][j][0] + bv.x;
            float v1 = acc[i][j][1] + bv.y;
            float v2 = acc[i][j][2] + bv.z;
            float v3 = acc[i][j][3] + bv.w;
            if (base16) {
                f16x4 bb = *(const f16x4*)&base16[yi];
                v0 += (float)bb[0]; v1 += (float)bb[1];
                v2 += (float)bb[2]; v3 += (float)bb[3];
            }
            f16x4 o4; o4[0] = (f16)v0; o4[1] = (f16)v1; o4[2] = (f16)v2; o4[3] = (f16)v3;
            *(f16x4*)&Y[yi] = o4;
        }
    }
}

// ---------------------------------------------------------------------------
// Weight prep: Wz (24,512,64)=Wx0[:, :64, :]^T; Wt0 (24,512,192)=[Wx0[64:72]|Wh0|0]^T;
// Wt1 (24,512,256)=[Wx1|Wh1]^T
// ---------------------------------------------------------------------------
__global__ __launch_bounds__(256) void prep_w01(
    const float* __restrict__ Wx0, const float* __restrict__ Wh0,
    const float* __restrict__ Wx1, const float* __restrict__ Wh1,
    f16* __restrict__ Wz, f16* __restrict__ Wt0, f16* __restrict__ Wt1)
{
    size_t idx = (size_t)blockIdx.x * 256 + threadIdx.x;
    const size_t nz = (size_t)Nn * 512 * 64;       // 786432
    const size_t n0 = (size_t)Nn * 512 * 192;      // 2359296
    const size_t n1 = (size_t)Nn * 512 * 256;      // 3145728
    if (idx < nz) {
        int k = idx & 63; int o = (idx >> 6) & 511; int n = (int)(idx >> 15);
        Wz[idx] = (f16)Wx0[((size_t)n * 72 + k) * 512 + o];
    } else if (idx < nz + n0) {
        size_t i2 = idx - nz;
        int k = (int)(i2 % 192);
        size_t no = i2 / 192;
        int o = (int)(no & 511); int n = (int)(no >> 9);
        float v = 0.f;
        if (k < 8) v = Wx0[((size_t)n * 72 + 64 + k) * 512 + o];
        else if (k < 136) v = Wh0[((size_t)n * 128 + (k - 8)) * 512 + o];
        Wt0[i2] = (f16)v;
    } else if (idx < nz + n0 + n1) {
        size_t i3 = idx - nz - n0;
        int k = (int)(i3 & 255);
        size_t no = i3 >> 8;
        int o = (int)(no & 511); int n = (int)(no >> 9);
        float v = (k < 128) ? Wx1[((size_t)n * 128 + k) * 512 + o]
                            : Wh1[((size_t)n * 128 + (k - 128)) * 512 + o];
        Wt1[i3] = (f16)v;
    }
}

// Wtf (24,256,128): o<128 -> fcW^T, else fc2W^T
__global__ __launch_bounds__(256) void prep_wf(
    const float* __restrict__ fcW, const float* __restrict__ fc2W,
    f16* __restrict__ Wtf)
{
    size_t idx = (size_t)blockIdx.x * 256 + threadIdx.x;
    if (idx >= (size_t)Nn * 256 * 128) return;
    int k = (int)(idx & 127);
    size_t no = idx >> 7;
    int o = (int)(no & 255); int n = (int)(no >> 8);
    float v = (o < 128) ? fcW[((size_t)n * 128 + k) * 128 + o]
                        : fc2W[((size_t)n * 128 + k) * 128 + (o - 128)];
    Wtf[idx] = (f16)v;
}

// Wti (256,256) = [ih1W | ih2W]^T ; bi (256) ; bcat (24,256)
__global__ __launch_bounds__(256) void prep_wi(
    const float* __restrict__ ih1W, const float* __restrict__ ih2W,
    const float* __restrict__ ih1b, const float* __restrict__ ih2b,
    const float* __restrict__ fcb, const float* __restrict__ fc2b,
    f16* __restrict__ Wti, float* __restrict__ bi, float* __restrict__ bcat)
{
    int idx = blockIdx.x * 256 + threadIdx.x;   // 65536
    int k = idx & 255, o = idx >> 8;
    Wti[idx] = (f16)((o < 128) ? ih1W[(size_t)k * 128 + o] : ih2W[(size_t)k * 128 + (o - 128)]);
    if (idx < 256) bi[idx] = (idx < 128) ? ih1b[idx] : ih2b[idx - 128];
    if (idx < Nn * 256) {
        int n = idx >> 8, oo = idx & 255;
        bcat[idx] = (oo < 128) ? fcb[n * 128 + oo] : fc2b[n * 128 + (oo - 128)];
    }
}

// xi2[b,n,0:8)=x, [136:192)=0 ([8:136) = h1, filled by mix_init/mixlstm); ls=x[:4]
__global__ __launch_bounds__(256) void init_xi(
    const float* __restrict__ x, f16* __restrict__ xi2, float* __restrict__ ls)
{
    size_t idx = (size_t)blockIdx.x * 256 + threadIdx.x;
    const size_t total = (size_t)Bsz * Nn * 192;
    if (idx < total) {
        size_t bn = idx / 192;
        int k = (int)(idx - bn * 192);
        if (k < 8) xi2[idx] = (f16)x[bn * 8 + k];
        else if (k >= 136) xi2[idx] = (f16)0.f;
    }
    if (idx < (size_t)Bsz * Nn * 4) {
        size_t bn = idx >> 2;
        ls[idx] = x[bn * 8 + (idx & 3)];
    }
}

// ---------------------------------------------------------------------------
// Init mix: Yhc (B,N,256) f16 = [h-pre | c-pre]; h0 -> xi2[8:136), l2cat[0:128),
// l2cat[128:256); c0 -> c1, c2 (fp32).
// ---------------------------------------------------------------------------
__global__ __launch_bounds__(256) void mix_init(
    const f16* __restrict__ Yhc, const float* __restrict__ G,
    f16* __restrict__ xi2, f16* __restrict__ l2cat,
    float* __restrict__ c1, float* __restrict__ c2)
{
    const int b = blockIdx.x;
    const int tid = threadIdx.x;
    __shared__ float sY[6144], sG[576];
    for (int i = tid; i < 576; i += 256) sG[i] = G[i];
    for (int v = tid; v < 768; v += 256) {
        int c8 = (v & 31) * 8, n = v >> 5;
        f16x8 t = *(const f16x8*)&Yhc[((size_t)b * Nn + n) * 256 + c8];
        float* d = &sY[n * 256 + c8];
#pragma unroll
        for (int u = 0; u < 8; u++) d[u] = (float)t[u];
    }
    __syncthreads();
    for (int w = tid; w < 3072; w += 256) {
        int o = w & 127, m = w >> 7;
        float ah = 0.f, ac = 0.f;
#pragma unroll
        for (int n = 0; n < 24; n++) {
            float g = sG[m * 24 + n];
            ah += g * sY[n * 256 + o];
            ac += g * sY[n * 256 + 128 + o];
        }
        size_t row = (size_t)b * Nn + m;
        f16 hf = (f16)ah;
        xi2[row * 192 + 8 + o] = hf;
        l2cat[row * 256 + o] = hf;
        l2cat[row * 256 + 128 + o] = hf;
        c1[row * 128 + o] = ac;
        c2[row * 128 + o] = ac;
    }
}

// ---------------------------------------------------------------------------
// G-mix + LSTM pointwise. Ypre (B,N,512) f16 pre-mix gates. c fp32 in/out.
// h written f16 to dstA (raw) and dstB (raw or tanh). grid (B, 2 j-tiles).
// ---------------------------------------------------------------------------
__global__ __launch_bounds__(256) void mixlstm(
    const f16* __restrict__ Ypre, const float* __restrict__ G,
    float* __restrict__ c,
    f16* __restrict__ dstA, int strideA,
    f16* __restrict__ dstB, int strideB, int tanhB)
{
    const int b = blockIdx.x;
    const int jt = blockIdx.y * 64;
    const int tid = threadIdx.x;
    __shared__ float sY[6144];   // n, gate, j(64)
    __shared__ float sG[576];
    for (int i = tid; i < 576; i += 256) sG[i] = G[i];
    for (int v = tid; v < 768; v += 256) {
        int j8 = (v & 7) * 8, g = (v >> 3) & 3, n = v >> 5;
        f16x8 t = *(const f16x8*)&Ypre[((size_t)b * Nn + n) * 512 + g * 128 + jt + j8];
        float* d = &sY[n * 256 + g * 64 + j8];
#pragma unroll
        for (int u = 0; u < 8; u++) d[u] = (float)t[u];
    }
    __syncthreads();
    for (int w = tid; w < 1536; w += 256) {
        int j = w & 63, m = w >> 6;
        float gi = 0.f, gf = 0.f, gg = 0.f, go = 0.f;
        const float* gr = &sG[m * 24];
#pragma unroll
        for (int n = 0; n < 24; n++) {
            float g = gr[n];
            gi += g * sY[n * 256 + j];
            gf += g * sY[n * 256 + 64 + j];
            gg += g * sY[n * 256 + 128 + j];
            go += g * sY[n * 256 + 192 + j];
        }
        int col = jt + j;
        size_t row = (size_t)b * Nn + m;
        float cv = c[row * 128 + col];
        float si = 1.f / (1.f + expf(-gi));
        float sf = 1.f / (1.f + expf(-gf));
        float so = 1.f / (1.f + expf(-go));
        float tg = tanhf(gg);
        cv = sf * cv + si * tg;
        c[row * 128 + col] = cv;
        float h = so * tanhf(cv);
        dstA[row * strideA + col] = (f16)h;
        dstB[row * strideB + col] = (f16)(tanhB ? tanhf(h) : h);
    }
}

// ---------------------------------------------------------------------------
// Final per-step: mix fc pre-acts + tanh, head matvecs, second mix, quat,
// outputs, update xi2[0:8) & loc_start. p (B,N,256) f16 = [fc1-pre | fc2-pre].
// ---------------------------------------------------------------------------
__global__ __launch_bounds__(256) void finstep(
    const f16* __restrict__ p, const float* __restrict__ G,
    const float* __restrict__ locW, const float* __restrict__ locb,
    const float* __restrict__ lzW, const float* __restrict__ lzb,
    float* __restrict__ ls, f16* __restrict__ xi2,
    float* __restrict__ out, int t)
{
    const int b = blockIdx.x;
    const int tid = threadIdx.x;
    __shared__ float sP[6144], sY1[3072], sY2[3072];
    __shared__ float sG[576];
    __shared__ float sLp[24][3], sZp[24][4], sL3[24][3], sZ3[24][4];
    for (int i = tid; i < 576; i += 256) sG[i] = G[i];
    for (int v = tid; v < 768; v += 256) {
        int c8 = (v & 31) * 8, n = v >> 5;
        f16x8 tv = *(const f16x8*)&p[((size_t)b * Nn + n) * 256 + c8];
        float* d = &sP[n * 256 + c8];
#pragma unroll
        for (int u = 0; u < 8; u++) d[u] = (float)tv[u];
    }
    __syncthreads();
    for (int w = tid; w < 3072; w += 256) {
        int o = w & 127, m = w >> 7;
        float a1 = 0.f, a2 = 0.f;
#pragma unroll
        for (int n = 0; n < 24; n++) {
            float g = sG[m * 24 + n];
            a1 += g * sP[n * 256 + o];
            a2 += g * sP[n * 256 + 128 + o];
        }
        sY1[w] = tanhf(a1);
        sY2[w] = tanhf(a2);
    }
    __syncthreads();
    if (tid < 72) {
        int m = tid / 3, j = tid - m * 3;
        float s = locb[j];
        for (int o = 0; o < 128; o++) s += sY1[m * 128 + o] * locW[o * 3 + j];
        sLp[m][j] = s;
    } else if (tid < 168) {
        int w2 = tid - 72; int m = w2 >> 2, j = w2 & 3;
        float s = lzb[j];
        for (int o = 0; o < 128; o++) s += sY2[m * 128 + o] * lzW[o * 4 + j];
        sZp[m][j] = s;
    }
    __syncthreads();
    if (tid < 72) {
        int m = tid / 3, j = tid - m * 3;
        float s = 0.f;
#pragma unroll
        for (int n = 0; n < 24; n++) s += sG[m * 24 + n] * sLp[n][j];
        sL3[m][j] = s;
    } else if (tid < 168) {
        int w2 = tid - 72; int m = w2 >> 2, j = w2 & 3;
        float s = 0.f;
#pragma unroll
        for (int n = 0; n < 24; n++) s += sG[m * 24 + n] * sZp[n][j];
        sZ3[m][j] = s;
    }
    __syncthreads();
    if (tid < 24) {
        int m = tid;
        float xx = sL3[m][0], xy = sL3[m][1], xz = sL3[m][2];
        float r = rsqrtf(1.f + xx * xx + xy * xy + xz * xz);
        float dw = r, dx = xx * r, dy = xy * r, dz = xz * r;
        size_t li = ((size_t)b * Nn + m) * 4;
        float qw = ls[li], qx = ls[li + 1], qy = ls[li + 2], qz = ls[li + 3];
        float lw = qw * dw - qx * dx - qy * dy - qz * dz;
        float lx = qw * dx + qx * dw + qy * dz - qz * dy;
        float ly = qw * dy - qx * dz + qy * dw + qz * dx;
        float lz = qw * dz + qx * dy - qy * dx + qz * dw;
        size_t oi = (((size_t)b * Tt + t) * Nn + m) * 4;
        out[oi + 0] = lw; out[oi + 1] = lx; out[oi + 2] = ly; out[oi + 3] = lz;
        size_t zi = (size_t)Bsz * Tt * Nn * 4 + oi;
        out[zi + 0] = sZ3[m][0]; out[zi + 1] = sZ3[m][1];
        out[zi + 2] = sZ3[m][2]; out[zi + 3] = sZ3[m][3];
        ls[li] = lw; ls[li + 1] = lx; ls[li + 2] = ly; ls[li + 3] = lz;
        size_t xb = ((size_t)b * Nn + m) * 192;
        xi2[xb + 0] = (f16)lw; xi2[xb + 1] = (f16)lx; xi2[xb + 2] = (f16)ly; xi2[xb + 3] = (f16)lz;
        xi2[xb + 4] = (f16)dw; xi2[xb + 5] = (f16)dx; xi2[xb + 6] = (f16)dy; xi2[xb + 7] = (f16)dz;
    }
}

extern "C" void kernel_launch(void* const* d_in, const int* in_sizes, int n_in,
                              void* d_out, int out_size, void* d_ws, size_t ws_size,
                              hipStream_t stream)
{
    const float* x    = (const float*)d_in[0];
    const float* enc  = (const float*)d_in[1];
    const float* z    = (const float*)d_in[2];
    const float* G    = (const float*)d_in[4];
    const float* Wx0  = (const float*)d_in[5];
    const float* Wh0  = (const float*)d_in[6];
    const float* b0i  = (const float*)d_in[7];
    const float* Wx1  = (const float*)d_in[8];
    const float* Wh1  = (const float*)d_in[9];
    const float* b1i  = (const float*)d_in[10];
    const float* fcW  = (const float*)d_in[11];
    const float* fcb  = (const float*)d_in[12];
    const float* fc2W = (const float*)d_in[13];
    const float* fc2b = (const float*)d_in[14];
    const float* ih1W = (const float*)d_in[15];
    const float* ih1b = (const float*)d_in[16];
    const float* ih2W = (const float*)d_in[17];
    const float* ih2b = (const float*)d_in[18];
    const float* locW = (const float*)d_in[19];
    const float* locb = (const float*)d_in[20];
    const float* lzW  = (const float*)d_in[21];
    const float* lzb  = (const float*)d_in[22];
    float* out = (float*)d_out;

    const size_t BN = (size_t)Bsz * Nn;
    char* wp = (char*)d_ws;
    size_t off = 0;
    auto carve = [&](size_t bytes) -> char* {
        char* pc = wp + off;
        off += (bytes + 255) & ~(size_t)255;
        return pc;
    };
    f16*   Wz     = (f16*)carve((size_t)Nn * 512 * 64 * 2);
    f16*   Wt0    = (f16*)carve((size_t)Nn * 512 * 192 * 2);
    f16*   Wt1    = (f16*)carve((size_t)Nn * 512 * 256 * 2);
    f16*   Wtf    = (f16*)carve((size_t)Nn * 256 * 128 * 2);
    f16*   Wti    = (f16*)carve((size_t)256 * 256 * 2);
    float* bcat   = (float*)carve((size_t)Nn * 256 * 4);
    float* bi     = (float*)carve(256 * 4);
    f16*   base1  = (f16*)carve(BN * 512 * 2);
    f16*   xi2    = (f16*)carve(BN * 192 * 2);
    f16*   l2cat  = (f16*)carve(BN * 256 * 2);
    f16*   yib    = (f16*)carve(BN * 128 * 2);
    float* c1     = (float*)carve(BN * 128 * 4);
    float* c2     = (float*)carve(BN * 128 * 4);
    float* ls     = (float*)carve(BN * 4 * 4);
    f16*   yp     = (f16*)carve(BN * 512 * 2);
    f16*   pbuf   = (f16*)carve(BN * 256 * 2);

    // ---- one-time prep ----
    prep_w01<<<24576, 256, 0, stream>>>(Wx0, Wh0, Wx1, Wh1, Wz, Wt0, Wt1);
    prep_wf<<<3072, 256, 0, stream>>>(fcW, fc2W, Wtf);
    prep_wi<<<256, 256, 0, stream>>>(ih1W, ih2W, ih1b, ih2b, fcb, fc2b, Wti, bi, bcat);
    init_xi<<<9216, 256, 0, stream>>>(x, xi2, ls);

    // base1 = z . Wx0[:,:64,:] + b0    (constant over all T steps)
    gemm_mfma<2, 4><<<dim3(8, 4, 24), 256, 0, stream>>>(
        nullptr, z, 64, Wz, (size_t)512 * 64, b0i, 512, nullptr, base1, 512);
    // init states: [h0|c0] from enc
    gemm_mfma<2, 4><<<dim3(4, 4, 24), 256, 0, stream>>>(
        nullptr, enc, 256, Wti, 0, bi, 0, nullptr, yp, 256);
    mix_init<<<512, 256, 0, stream>>>(yp, G, xi2, l2cat, c1, c2);

    // ---- T sequential steps ----
    for (int t = 0; t < Tt; t++) {
        gemm_mfma<2, 4><<<dim3(8, 4, 24), 256, 0, stream>>>(
            xi2, nullptr, 192, Wt0, (size_t)512 * 192, nullptr, 0, base1, yp, 512);
        mixlstm<<<dim3(512, 2), 256, 0, stream>>>(yp, G, c1, xi2 + 8, 192, l2cat, 256, 0);
        gemm_mfma<2, 4><<<dim3(8, 4, 24), 256, 0, stream>>>(
            l2cat, nullptr, 256, Wt1, (size_t)512 * 256, b1i, 512, nullptr, yp, 512);
        mixlstm<<<dim3(512, 2), 256, 0, stream>>>(yp, G, c2, l2cat + 128, 256, yib, 128, 1);
        gemm_mfma<2, 4><<<dim3(4, 4, 24), 256, 0, stream>>>(
            yib, nullptr, 128, Wtf, (size_t)256 * 128, bcat, 256, nullptr, pbuf, 256);
        finstep<<<512, 256, 0, stream>>>(pbuf, G, locW, locb, lzW, lzb, ls, xi2, out, t);
    }
}